// Round 1
// baseline (1260.936 us; speedup 1.0000x reference)
//
#include <hip/hip_runtime.h>
#include <math.h>

#define EMBED  1024
#define DSTATE 16
#define DCONV  4
#define DTRANK 64
#define BB     2
#define TT     2048
#define M_TOK  (BB*TT)      // 4096 token rows
#define SSMW   96           // dt_rank + 2*DSTATE
#define NCHUNK 8
#define CLEN   (TT/NCHUNK)  // 256

__device__ __forceinline__ float silu_f(float x) {
    return x / (1.0f + __expf(-x));
}
__device__ __forceinline__ float softplus_f(float x) {
    // log(1+exp(x)) stable form
    return fmaxf(x, 0.0f) + log1pf(__expf(-fabsf(x)));
}

// ---------------------------------------------------------------------------
// C[m,n] = sum_k A[m,k] * W[n,k] (+ bias[n]) (+ C_old if accumulate) (+ act)
// fp32 tiled: 64x64 tile, BK=16, 256 threads, 4x4 microtile.
// ACT: 0 = none, 1 = softplus
// ---------------------------------------------------------------------------
template<int ACT>
__global__ __launch_bounds__(256)
void gemm_tn(const float* __restrict__ A, int lda,
             const float* __restrict__ W, int ldw,
             const float* __restrict__ bias,
             float* __restrict__ C, int ldc,
             int M, int N, int K, int accumulate)
{
    __shared__ float As[16][64];   // [k][m] transposed store
    __shared__ float Ws[16][64];   // [k][n]

    const int tid  = threadIdx.x;
    const int tx   = tid & 15;     // n micro-group
    const int ty   = tid >> 4;     // m micro-group
    const int m0   = blockIdx.y * 64;
    const int n0   = blockIdx.x * 64;
    const int kloc = tid & 15;
    const int rloc = tid >> 4;     // 0..15

    float acc[4][4] = {};

    for (int kt = 0; kt < K; kt += 16) {
        #pragma unroll
        for (int i = 0; i < 4; ++i) {
            int m = rloc + i * 16;
            As[kloc][m] = A[(size_t)(m0 + m) * lda + kt + kloc];
        }
        #pragma unroll
        for (int i = 0; i < 4; ++i) {
            int n = rloc + i * 16;
            float v = 0.0f;
            if (n0 + n < N) v = W[(size_t)(n0 + n) * ldw + kt + kloc];
            Ws[kloc][n] = v;
        }
        __syncthreads();
        #pragma unroll
        for (int kk = 0; kk < 16; ++kk) {
            float4 a = *reinterpret_cast<const float4*>(&As[kk][ty * 4]);
            float4 w = *reinterpret_cast<const float4*>(&Ws[kk][tx * 4]);
            acc[0][0] = fmaf(a.x, w.x, acc[0][0]);
            acc[0][1] = fmaf(a.x, w.y, acc[0][1]);
            acc[0][2] = fmaf(a.x, w.z, acc[0][2]);
            acc[0][3] = fmaf(a.x, w.w, acc[0][3]);
            acc[1][0] = fmaf(a.y, w.x, acc[1][0]);
            acc[1][1] = fmaf(a.y, w.y, acc[1][1]);
            acc[1][2] = fmaf(a.y, w.z, acc[1][2]);
            acc[1][3] = fmaf(a.y, w.w, acc[1][3]);
            acc[2][0] = fmaf(a.z, w.x, acc[2][0]);
            acc[2][1] = fmaf(a.z, w.y, acc[2][1]);
            acc[2][2] = fmaf(a.z, w.z, acc[2][2]);
            acc[2][3] = fmaf(a.z, w.w, acc[2][3]);
            acc[3][0] = fmaf(a.w, w.x, acc[3][0]);
            acc[3][1] = fmaf(a.w, w.y, acc[3][1]);
            acc[3][2] = fmaf(a.w, w.z, acc[3][2]);
            acc[3][3] = fmaf(a.w, w.w, acc[3][3]);
        }
        __syncthreads();
    }

    #pragma unroll
    for (int i = 0; i < 4; ++i) {
        int m = m0 + ty * 4 + i;
        #pragma unroll
        for (int j = 0; j < 4; ++j) {
            int n = n0 + tx * 4 + j;
            if (n < N) {
                float v = acc[i][j];
                if (bias) v += bias[n];
                if (accumulate) v += C[(size_t)m * ldc + n];
                if (ACT == 1) v = softplus_f(v);
                C[(size_t)m * ldc + n] = v;
            }
        }
    }
}

// ---------------------------------------------------------------------------
// depthwise causal conv1d (k=4, left pad 3) + bias + SiLU
// x_in = first EMBED columns of xr (row stride 2*EMBED)
// ---------------------------------------------------------------------------
__global__ __launch_bounds__(256)
void conv_silu_kernel(const float* __restrict__ xr,
                      const float* __restrict__ conv_w,
                      const float* __restrict__ conv_b,
                      float* __restrict__ xc)
{
    int idx = blockIdx.x * blockDim.x + threadIdx.x;   // over B*T*D
    if (idx >= BB * TT * EMBED) return;
    int d = idx & (EMBED - 1);
    int t = (idx >> 10) & (TT - 1);
    int b = idx >> 21;

    float w0 = conv_w[d * 4 + 0];
    float w1 = conv_w[d * 4 + 1];
    float w2 = conv_w[d * 4 + 2];
    float w3 = conv_w[d * 4 + 3];

    size_t base = ((size_t)(b * TT + t)) * (2 * EMBED) + d;
    float s = conv_b[d];
    if (t >= 3) s = fmaf(w0, xr[base - 3 * 2 * EMBED], s);
    if (t >= 2) s = fmaf(w1, xr[base - 2 * 2 * EMBED], s);
    if (t >= 1) s = fmaf(w2, xr[base - 1 * 2 * EMBED], s);
    s = fmaf(w3, xr[base], s);
    xc[(size_t)(b * TT + t) * EMBED + d] = silu_f(s);
}

// ---------------------------------------------------------------------------
// Scan pass A: per (b,d,n,chunk) local scan from h=0; store h_out and prod(dA)
// block = 256 threads = 16 d x 16 n; grid = BB * NCHUNK * (EMBED/16)
// ---------------------------------------------------------------------------
__global__ __launch_bounds__(256)
void scan_chunk_kernel(const float* __restrict__ delta,
                       const float* __restrict__ xc,
                       const float* __restrict__ ssm,
                       const float* __restrict__ A_log,
                       float* __restrict__ hout,
                       float* __restrict__ aprod)
{
    int n  = threadIdx.x & 15;
    int dl = threadIdx.x >> 4;
    int blk = blockIdx.x;
    int dg    = blk & 63;          // EMBED/16 = 64
    int chunk = (blk >> 6) & (NCHUNK - 1);
    int b     = blk >> 9;
    int d = dg * 16 + dl;

    float An = -__expf(A_log[n]);
    float h = 0.0f, ap = 1.0f;
    int t0 = chunk * CLEN;
    for (int t = t0; t < t0 + CLEN; ++t) {
        size_t row = (size_t)(b * TT + t);
        float dv = delta[row * EMBED + d];
        float xv = xc[row * EMBED + d];
        float Bn = ssm[row * SSMW + DTRANK + n];
        float dA = __expf(dv * An);
        h = fmaf(dA, h, dv * Bn * xv);
        ap *= dA;
    }
    int idx = ((b * EMBED + d) * DSTATE + n) * NCHUNK + chunk;
    hout[idx]  = h;
    aprod[idx] = ap;
}

// ---------------------------------------------------------------------------
// Scan pass B: sequential combine over chunks per (b,d,n); store h entering
// each chunk.
// ---------------------------------------------------------------------------
__global__ __launch_bounds__(256)
void scan_combine_kernel(const float* __restrict__ hout,
                         const float* __restrict__ aprod,
                         float* __restrict__ hin)
{
    int idx = blockIdx.x * blockDim.x + threadIdx.x;   // B*EMBED*DSTATE
    if (idx >= BB * EMBED * DSTATE) return;
    float h = 0.0f;
    #pragma unroll
    for (int c = 0; c < NCHUNK; ++c) {
        hin[idx * NCHUNK + c] = h;
        h = fmaf(aprod[idx * NCHUNK + c], h, hout[idx * NCHUNK + c]);
    }
}

// ---------------------------------------------------------------------------
// Scan pass C: re-scan with correct h_in, reduce over n (16-lane shfl),
// add D skip, gate with silu(res), write y.
// ---------------------------------------------------------------------------
__global__ __launch_bounds__(256)
void scan_apply_kernel(const float* __restrict__ delta,
                       const float* __restrict__ xc,
                       const float* __restrict__ ssm,
                       const float* __restrict__ A_log,
                       const float* __restrict__ D_param,
                       const float* __restrict__ xr,
                       const float* __restrict__ hin,
                       float* __restrict__ y)
{
    int n  = threadIdx.x & 15;
    int dl = threadIdx.x >> 4;
    int blk = blockIdx.x;
    int dg    = blk & 63;
    int chunk = (blk >> 6) & (NCHUNK - 1);
    int b     = blk >> 9;
    int d = dg * 16 + dl;

    float An = -__expf(A_log[n]);
    float Dd = D_param[d];
    float h = hin[((b * EMBED + d) * DSTATE + n) * NCHUNK + chunk];
    int t0 = chunk * CLEN;
    for (int t = t0; t < t0 + CLEN; ++t) {
        size_t row = (size_t)(b * TT + t);
        float dv = delta[row * EMBED + d];
        float xv = xc[row * EMBED + d];
        float Bn = ssm[row * SSMW + DTRANK + n];
        float Cn = ssm[row * SSMW + DTRANK + DSTATE + n];
        float dA = __expf(dv * An);
        h = fmaf(dA, h, dv * Bn * xv);
        float contrib = h * Cn;
        contrib += __shfl_xor(contrib, 1, 16);
        contrib += __shfl_xor(contrib, 2, 16);
        contrib += __shfl_xor(contrib, 4, 16);
        contrib += __shfl_xor(contrib, 8, 16);
        if (n == 0) {
            float yv = contrib + xv * Dd;
            float rv = xr[row * (2 * EMBED) + EMBED + d];
            y[row * EMBED + d] = yv * silu_f(rv);
        }
    }
}

// ---------------------------------------------------------------------------
extern "C" void kernel_launch(void* const* d_in, const int* in_sizes, int n_in,
                              void* d_out, int out_size, void* d_ws, size_t ws_size,
                              hipStream_t stream) {
    const float* x      = (const float*)d_in[0];
    const float* in_w   = (const float*)d_in[1];
    const float* in_b   = (const float*)d_in[2];
    const float* conv_w = (const float*)d_in[3];
    const float* conv_b = (const float*)d_in[4];
    const float* xp_w   = (const float*)d_in[5];
    const float* xp_b   = (const float*)d_in[6];
    const float* dt_w   = (const float*)d_in[7];
    const float* dt_b   = (const float*)d_in[8];
    const float* A_log  = (const float*)d_in[9];
    const float* Dp     = (const float*)d_in[10];
    const float* out_w  = (const float*)d_in[11];
    const float* out_b  = (const float*)d_in[12];
    const float* skip_w = (const float*)d_in[13];
    const float* skip_b = (const float*)d_in[14];
    float* out = (float*)d_out;

    float* ws    = (float*)d_ws;
    float* xr    = ws;                                   // 4096*2048 = 8M
    float* xc    = xr    + (size_t)M_TOK * 2 * EMBED;    // 4M
    float* ssm   = xc    + (size_t)M_TOK * EMBED;        // 4096*96 (pad 128)
    float* delta = ssm   + (size_t)M_TOK * 128;          // 4M
    float* yb    = delta + (size_t)M_TOK * EMBED;        // 4M
    float* hout  = yb    + (size_t)M_TOK * EMBED;        // 256K
    float* aprod = hout  + (size_t)BB * EMBED * DSTATE * NCHUNK;
    float* hin   = aprod + (size_t)BB * EMBED * DSTATE * NCHUNK;

    dim3 blk(256);

    // 1) xr = x @ in_proj_w^T + in_proj_b        (4096 x 2048, K=1024)
    gemm_tn<0><<<dim3(2 * EMBED / 64, M_TOK / 64), blk, 0, stream>>>(
        x, EMBED, in_w, EMBED, in_b, xr, 2 * EMBED, M_TOK, 2 * EMBED, EMBED, 0);

    // 2) xc = silu(causal_dwconv(x_in) + conv_b)
    conv_silu_kernel<<<(M_TOK * EMBED + 255) / 256, blk, 0, stream>>>(
        xr, conv_w, conv_b, xc);

    // 3) ssm = xc @ x_proj_w^T + x_proj_b        (4096 x 96, K=1024)
    gemm_tn<0><<<dim3((SSMW + 63) / 64, M_TOK / 64), blk, 0, stream>>>(
        xc, EMBED, xp_w, EMBED, xp_b, ssm, SSMW, M_TOK, SSMW, EMBED, 0);

    // 4) delta = softplus(ssm[:, :64] @ dt_proj_w^T + dt_proj_b)  (4096 x 1024, K=64)
    gemm_tn<1><<<dim3(EMBED / 64, M_TOK / 64), blk, 0, stream>>>(
        ssm, SSMW, dt_w, DTRANK, dt_b, delta, EMBED, M_TOK, EMBED, DTRANK, 0);

    // 5) selective scan (3-pass chunked)
    scan_chunk_kernel<<<BB * NCHUNK * (EMBED / 16), blk, 0, stream>>>(
        delta, xc, ssm, A_log, hout, aprod);
    scan_combine_kernel<<<(BB * EMBED * DSTATE + 255) / 256, blk, 0, stream>>>(
        hout, aprod, hin);
    scan_apply_kernel<<<BB * NCHUNK * (EMBED / 16), blk, 0, stream>>>(
        delta, xc, ssm, A_log, Dp, xr, hin, yb);

    // 6) out = yb @ out_proj_w^T + out_b  then += x @ skip_proj_w^T + skip_b
    gemm_tn<0><<<dim3(EMBED / 64, M_TOK / 64), blk, 0, stream>>>(
        yb, EMBED, out_w, EMBED, out_b, out, EMBED, M_TOK, EMBED, EMBED, 0);
    gemm_tn<0><<<dim3(EMBED / 64, M_TOK / 64), blk, 0, stream>>>(
        x, EMBED, skip_w, EMBED, skip_b, out, EMBED, M_TOK, EMBED, EMBED, 1);
}

// Round 2
// 501.167 us; speedup vs baseline: 2.5160x; 2.5160x over previous
//
#include <hip/hip_runtime.h>
#include <math.h>

#define EMBED  1024
#define DSTATE 16
#define DCONV  4
#define DTRANK 64
#define BB     2
#define TT     2048
#define M_TOK  (BB*TT)      // 4096 token rows
#define SSMW   96           // dt_rank + 2*DSTATE
#define NCHUNK 8
#define CLEN   (TT/NCHUNK)  // 256

typedef __attribute__((ext_vector_type(8))) __bf16 bf16x8;
typedef __attribute__((ext_vector_type(4))) float floatx4;

__device__ __forceinline__ float silu_f(float x) {
    return x / (1.0f + __expf(-x));
}
__device__ __forceinline__ float softplus_f(float x) {
    return fmaxf(x, 0.0f) + log1pf(__expf(-fabsf(x)));
}
__device__ __forceinline__ unsigned short f2bf(float f) {
    union { float f; unsigned int u; } v; v.f = f;
    unsigned int u = v.u;
    return (unsigned short)((u + 0x7fffu + ((u >> 16) & 1u)) >> 16);
}
__device__ __forceinline__ float bf2f(unsigned short s) {
    union { unsigned int u; float f; } v; v.u = ((unsigned int)s) << 16;
    return v.f;
}
__device__ __forceinline__ void async16(unsigned short* lds, const unsigned short* g) {
    __builtin_amdgcn_global_load_lds(
        (const __attribute__((address_space(1))) unsigned int*)g,
        (__attribute__((address_space(3))) unsigned int*)lds, 16, 0, 0);
}

// ---------------------------------------------------------------------------
// bf16 MFMA GEMM: C[m,n] = sum_k A[m,k]*W[n,k] + bias  (A,W bf16, acc fp32)
// 128x128 tile, BK=32, 256 threads = 4 waves in 2x2, 4x4 16x16x32 tiles/wave.
// EPI: 0 = fp32 store (+bias)            [in_proj -> xr]
//      1 = guarded n<96 fp32 ssm store; n<64 also bf16 into aux  [x_proj]
//      2 = softplus -> bf16 into aux     [dt_proj -> delta]
//      3 = fp32 store + bias + bias2     [fused out+skip -> out]
// M assumed multiple of 128; staging assumes A has >=128 rows per tile and
// W buffer padded to n-tile multiple of 128 rows.
// ---------------------------------------------------------------------------
template<int EPI>
__global__ __launch_bounds__(256)
void gemm_bf16(const unsigned short* __restrict__ A, int lda,
               const unsigned short* __restrict__ W, int ldw,
               const float* __restrict__ bias, const float* __restrict__ bias2,
               float* __restrict__ C, int ldc, int K,
               unsigned short* __restrict__ aux)
{
    __shared__ unsigned short As[128 * 32];
    __shared__ unsigned short Ws[128 * 32];

    const int tid  = threadIdx.x;
    const int m0   = blockIdx.y * 128;
    const int n0   = blockIdx.x * 128;
    const int wid  = tid >> 6;
    const int lane = tid & 63;
    const int wm   = wid >> 1, wn = wid & 1;
    const int lr   = lane & 15;   // m (A-frag) / n (B-frag) / col (C)
    const int lq   = lane >> 4;   // quad

    const int l0 = tid,        row0 = l0 >> 2, kc0 = (l0 & 3) * 8;
    const int l1 = tid + 256,  row1 = l1 >> 2, kc1 = (l1 & 3) * 8;

    floatx4 acc[4][4] = {};

    for (int kt = 0; kt < K; kt += 32) {
        async16(&As[l0 * 8], A + (size_t)(m0 + row0) * lda + kt + kc0);
        async16(&As[l1 * 8], A + (size_t)(m0 + row1) * lda + kt + kc1);
        async16(&Ws[l0 * 8], W + (size_t)(n0 + row0) * ldw + kt + kc0);
        async16(&Ws[l1 * 8], W + (size_t)(n0 + row1) * ldw + kt + kc1);
        __syncthreads();

        bf16x8 af[4], bfr[4];
        #pragma unroll
        for (int i = 0; i < 4; ++i)
            af[i] = *(const bf16x8*)&As[(wm * 64 + i * 16 + lr) * 32 + lq * 8];
        #pragma unroll
        for (int i = 0; i < 4; ++i)
            bfr[i] = *(const bf16x8*)&Ws[(wn * 64 + i * 16 + lr) * 32 + lq * 8];

        #pragma unroll
        for (int mi = 0; mi < 4; ++mi)
            #pragma unroll
            for (int ni = 0; ni < 4; ++ni)
                acc[mi][ni] = __builtin_amdgcn_mfma_f32_16x16x32_bf16(
                    af[mi], bfr[ni], acc[mi][ni], 0, 0, 0);
        __syncthreads();
    }

    #pragma unroll
    for (int mi = 0; mi < 4; ++mi) {
        #pragma unroll
        for (int ni = 0; ni < 4; ++ni) {
            int nb = n0 + wn * 64 + ni * 16 + lr;
            #pragma unroll
            for (int r = 0; r < 4; ++r) {
                int m = m0 + wm * 64 + mi * 16 + lq * 4 + r;
                float v = acc[mi][ni][r];
                if (EPI == 0) {
                    C[(size_t)m * ldc + nb] = v + bias[nb];
                } else if (EPI == 1) {
                    if (nb < SSMW) {
                        float o = v + bias[nb];
                        C[(size_t)m * SSMW + nb] = o;
                        if (nb < DTRANK) aux[(size_t)m * DTRANK + nb] = f2bf(o);
                    }
                } else if (EPI == 2) {
                    aux[(size_t)m * ldc + nb] = f2bf(softplus_f(v + bias[nb]));
                } else {
                    C[(size_t)m * ldc + nb] = v + bias[nb] + bias2[nb];
                }
            }
        }
    }
}

// ---------------------------------------------------------------------------
// conversion / packing kernels (fp32 -> bf16), 4 elem/thread
// ---------------------------------------------------------------------------
__global__ __launch_bounds__(256)
void cvt_f32_bf16(const float* __restrict__ src, unsigned short* __restrict__ dst, int n)
{
    int i = (blockIdx.x * 256 + threadIdx.x) * 4;
    if (i >= n) return;
    float4 v = *(const float4*)&src[i];
    ushort4 o = { f2bf(v.x), f2bf(v.y), f2bf(v.z), f2bf(v.w) };
    *(ushort4*)&dst[i] = o;
}

// xp_w (96x1024) -> padded (128x1024), zero pad rows
__global__ __launch_bounds__(256)
void cvt_pad_xp(const float* __restrict__ src, unsigned short* __restrict__ dst)
{
    int i = (blockIdx.x * 256 + threadIdx.x) * 4;          // over 128*1024
    if (i >= 128 * EMBED) return;
    int row = i >> 10;
    ushort4 o = { 0, 0, 0, 0 };
    if (row < SSMW) {
        float4 v = *(const float4*)&src[i];
        o = { f2bf(v.x), f2bf(v.y), f2bf(v.z), f2bf(v.w) };
    }
    *(ushort4*)&dst[i] = o;
}

// Wcat[n, 0:1024] = out_w[n,:], Wcat[n, 1024:2048] = skip_w[n,:]
__global__ __launch_bounds__(256)
void cvt_cat_w(const float* __restrict__ ow, const float* __restrict__ sw,
               unsigned short* __restrict__ dst)
{
    int i = (blockIdx.x * 256 + threadIdx.x) * 4;          // over 1024*2048
    if (i >= EMBED * 2 * EMBED) return;
    int n = i >> 11, k = i & 2047;
    const float* s = (k < EMBED) ? &ow[(size_t)n * EMBED + k]
                                 : &sw[(size_t)n * EMBED + (k - EMBED)];
    float4 v = *(const float4*)s;
    ushort4 o = { f2bf(v.x), f2bf(v.y), f2bf(v.z), f2bf(v.w) };
    *(ushort4*)&dst[i] = o;
}

// x (4096x1024) -> Acat[m, 1024:2048]
__global__ __launch_bounds__(256)
void cvt_x(const float* __restrict__ x, unsigned short* __restrict__ Acat)
{
    int i = (blockIdx.x * 256 + threadIdx.x) * 4;          // over 4096*1024
    if (i >= M_TOK * EMBED) return;
    int m = i >> 10, k = i & 1023;
    float4 v = *(const float4*)&x[i];
    ushort4 o = { f2bf(v.x), f2bf(v.y), f2bf(v.z), f2bf(v.w) };
    *(ushort4*)&Acat[(size_t)m * 2 * EMBED + EMBED + k] = o;
}

// ---------------------------------------------------------------------------
// depthwise causal conv1d (k=4) + bias + SiLU -> xc bf16
// ---------------------------------------------------------------------------
__global__ __launch_bounds__(256)
void conv_silu_kernel(const float* __restrict__ xr,
                      const float* __restrict__ conv_w,
                      const float* __restrict__ conv_b,
                      unsigned short* __restrict__ xcb)
{
    int idx = blockIdx.x * blockDim.x + threadIdx.x;   // over B*T*D
    if (idx >= BB * TT * EMBED) return;
    int d = idx & (EMBED - 1);
    int t = (idx >> 10) & (TT - 1);
    int b = idx >> 21;

    float w0 = conv_w[d * 4 + 0];
    float w1 = conv_w[d * 4 + 1];
    float w2 = conv_w[d * 4 + 2];
    float w3 = conv_w[d * 4 + 3];

    size_t base = ((size_t)(b * TT + t)) * (2 * EMBED) + d;
    float s = conv_b[d];
    if (t >= 3) s = fmaf(w0, xr[base - 3 * 2 * EMBED], s);
    if (t >= 2) s = fmaf(w1, xr[base - 2 * 2 * EMBED], s);
    if (t >= 1) s = fmaf(w2, xr[base - 1 * 2 * EMBED], s);
    s = fmaf(w3, xr[base], s);
    xcb[(size_t)(b * TT + t) * EMBED + d] = f2bf(silu_f(s));
}

// ---------------------------------------------------------------------------
// Scan pass A: per (b,d,n,chunk) local scan from h=0; store h_out, prod(dA)
// ---------------------------------------------------------------------------
__global__ __launch_bounds__(256)
void scan_chunk_kernel(const unsigned short* __restrict__ deltab,
                       const unsigned short* __restrict__ xcb,
                       const float* __restrict__ ssm,
                       const float* __restrict__ A_log,
                       float* __restrict__ hout,
                       float* __restrict__ aprod)
{
    int n  = threadIdx.x & 15;
    int dl = threadIdx.x >> 4;
    int blk = blockIdx.x;
    int dg    = blk & 63;
    int chunk = (blk >> 6) & (NCHUNK - 1);
    int b     = blk >> 9;
    int d = dg * 16 + dl;

    float An = -__expf(A_log[n]);
    float h = 0.0f, ap = 1.0f;
    int t0 = chunk * CLEN;
    for (int t = t0; t < t0 + CLEN; ++t) {
        size_t row = (size_t)(b * TT + t);
        float dv = bf2f(deltab[row * EMBED + d]);
        float xv = bf2f(xcb[row * EMBED + d]);
        float Bn = ssm[row * SSMW + DTRANK + n];
        float dA = __expf(dv * An);
        h = fmaf(dA, h, dv * Bn * xv);
        ap *= dA;
    }
    int idx = ((b * EMBED + d) * DSTATE + n) * NCHUNK + chunk;
    hout[idx]  = h;
    aprod[idx] = ap;
}

// ---------------------------------------------------------------------------
// Scan pass B: sequential combine over chunks per (b,d,n)
// ---------------------------------------------------------------------------
__global__ __launch_bounds__(256)
void scan_combine_kernel(const float* __restrict__ hout,
                         const float* __restrict__ aprod,
                         float* __restrict__ hin)
{
    int idx = blockIdx.x * blockDim.x + threadIdx.x;   // B*EMBED*DSTATE
    if (idx >= BB * EMBED * DSTATE) return;
    float h = 0.0f;
    #pragma unroll
    for (int c = 0; c < NCHUNK; ++c) {
        hin[idx * NCHUNK + c] = h;
        h = fmaf(aprod[idx * NCHUNK + c], h, hout[idx * NCHUNK + c]);
    }
}

// ---------------------------------------------------------------------------
// Scan pass C: re-scan with h_in, reduce over n, D skip, gate, write yb bf16
// into Acat[:, 0:1024]
// ---------------------------------------------------------------------------
__global__ __launch_bounds__(256)
void scan_apply_kernel(const unsigned short* __restrict__ deltab,
                       const unsigned short* __restrict__ xcb,
                       const float* __restrict__ ssm,
                       const float* __restrict__ A_log,
                       const float* __restrict__ D_param,
                       const float* __restrict__ xr,
                       const float* __restrict__ hin,
                       unsigned short* __restrict__ Acat)
{
    int n  = threadIdx.x & 15;
    int dl = threadIdx.x >> 4;
    int blk = blockIdx.x;
    int dg    = blk & 63;
    int chunk = (blk >> 6) & (NCHUNK - 1);
    int b     = blk >> 9;
    int d = dg * 16 + dl;

    float An = -__expf(A_log[n]);
    float Dd = D_param[d];
    float h = hin[((b * EMBED + d) * DSTATE + n) * NCHUNK + chunk];
    int t0 = chunk * CLEN;
    for (int t = t0; t < t0 + CLEN; ++t) {
        size_t row = (size_t)(b * TT + t);
        float dv = bf2f(deltab[row * EMBED + d]);
        float xv = bf2f(xcb[row * EMBED + d]);
        float Bn = ssm[row * SSMW + DTRANK + n];
        float Cn = ssm[row * SSMW + DTRANK + DSTATE + n];
        float dA = __expf(dv * An);
        h = fmaf(dA, h, dv * Bn * xv);
        float contrib = h * Cn;
        contrib += __shfl_xor(contrib, 1, 16);
        contrib += __shfl_xor(contrib, 2, 16);
        contrib += __shfl_xor(contrib, 4, 16);
        contrib += __shfl_xor(contrib, 8, 16);
        if (n == 0) {
            float yv = contrib + xv * Dd;
            float rv = xr[row * (2 * EMBED) + EMBED + d];
            Acat[row * 2 * EMBED + d] = f2bf(yv * silu_f(rv));
        }
    }
}

// ---------------------------------------------------------------------------
extern "C" void kernel_launch(void* const* d_in, const int* in_sizes, int n_in,
                              void* d_out, int out_size, void* d_ws, size_t ws_size,
                              hipStream_t stream) {
    const float* x      = (const float*)d_in[0];
    const float* in_w   = (const float*)d_in[1];
    const float* in_b   = (const float*)d_in[2];
    const float* conv_w = (const float*)d_in[3];
    const float* conv_b = (const float*)d_in[4];
    const float* xp_w   = (const float*)d_in[5];
    const float* xp_b   = (const float*)d_in[6];
    const float* dt_w   = (const float*)d_in[7];
    const float* dt_b   = (const float*)d_in[8];
    const float* A_log  = (const float*)d_in[9];
    const float* Dp     = (const float*)d_in[10];
    const float* out_w  = (const float*)d_in[11];
    const float* out_b  = (const float*)d_in[12];
    const float* skip_w = (const float*)d_in[13];
    const float* skip_b = (const float*)d_in[14];
    float* out = (float*)d_out;

    // workspace layout
    float* ws    = (float*)d_ws;
    float* xr    = ws;                                    // 4096*2048 fp32
    float* ssm   = xr   + (size_t)M_TOK * 2 * EMBED;      // 4096*96 fp32
    float* hout  = ssm  + (size_t)M_TOK * SSMW;           // 256K
    float* aprod = hout + (size_t)BB * EMBED * DSTATE * NCHUNK;
    float* hin   = aprod + (size_t)BB * EMBED * DSTATE * NCHUNK;
    unsigned short* Acat = (unsigned short*)(hin + (size_t)BB * EMBED * DSTATE * NCHUNK);
    unsigned short* xcb  = Acat + (size_t)M_TOK * 2 * EMBED;   // 4096*1024 bf16
    unsigned short* dltb = xcb  + (size_t)M_TOK * EMBED;       // 4096*1024 bf16
    unsigned short* dtin = dltb + (size_t)M_TOK * EMBED;       // 4096*64 bf16
    unsigned short* inwb = dtin + (size_t)M_TOK * DTRANK;      // 2048*1024 bf16
    unsigned short* xpwb = inwb + (size_t)2 * EMBED * EMBED;   // 128*1024 bf16
    unsigned short* dtwb = xpwb + (size_t)128 * EMBED;         // 1024*64 bf16
    unsigned short* wcat = dtwb + (size_t)EMBED * DTRANK;      // 1024*2048 bf16

    dim3 blk(256);

    // pack weights + x
    cvt_f32_bf16<<<(2 * EMBED * EMBED / 4 + 255) / 256, blk, 0, stream>>>(in_w, inwb, 2 * EMBED * EMBED);
    cvt_f32_bf16<<<(EMBED * DTRANK / 4 + 255) / 256, blk, 0, stream>>>(dt_w, dtwb, EMBED * DTRANK);
    cvt_pad_xp<<<(128 * EMBED / 4 + 255) / 256, blk, 0, stream>>>(xp_w, xpwb);
    cvt_cat_w<<<(EMBED * 2 * EMBED / 4 + 255) / 256, blk, 0, stream>>>(out_w, skip_w, wcat);
    cvt_x<<<(M_TOK * EMBED / 4 + 255) / 256, blk, 0, stream>>>(x, Acat);

    // 1) xr = x @ in_proj_w^T + b   (4096 x 2048, K=1024) -- A = Acat[:,1024:]
    gemm_bf16<0><<<dim3(2 * EMBED / 128, M_TOK / 128), blk, 0, stream>>>(
        Acat + EMBED, 2 * EMBED, inwb, EMBED, in_b, nullptr, xr, 2 * EMBED, EMBED, nullptr);

    // 2) xc = silu(causal_dwconv + bias) -> bf16
    conv_silu_kernel<<<(M_TOK * EMBED + 255) / 256, blk, 0, stream>>>(xr, conv_w, conv_b, xcb);

    // 3) ssm = xc @ x_proj_w^T + b  (4096 x 96, K=1024); also dtin bf16 (n<64)
    gemm_bf16<1><<<dim3(1, M_TOK / 128), blk, 0, stream>>>(
        xcb, EMBED, xpwb, EMBED, xp_b, nullptr, ssm, SSMW, EMBED, dtin);

    // 4) delta = softplus(dtin @ dt_w^T + b) -> bf16  (4096 x 1024, K=64)
    gemm_bf16<2><<<dim3(EMBED / 128, M_TOK / 128), blk, 0, stream>>>(
        dtin, DTRANK, dtwb, DTRANK, dt_b, nullptr, nullptr, EMBED, DTRANK, dltb);

    // 5) selective scan (3-pass chunked); pass C writes yb bf16 into Acat[:, :1024]
    scan_chunk_kernel<<<BB * NCHUNK * (EMBED / 16), blk, 0, stream>>>(
        dltb, xcb, ssm, A_log, hout, aprod);
    scan_combine_kernel<<<(BB * EMBED * DSTATE + 255) / 256, blk, 0, stream>>>(
        hout, aprod, hin);
    scan_apply_kernel<<<BB * NCHUNK * (EMBED / 16), blk, 0, stream>>>(
        dltb, xcb, ssm, A_log, Dp, xr, hin, Acat);

    // 6) out = [yb|x] @ [out_w|skip_w]^T + out_b + skip_b  (4096 x 1024, K=2048)
    gemm_bf16<3><<<dim3(EMBED / 128, M_TOK / 128), blk, 0, stream>>>(
        Acat, 2 * EMBED, wcat, 2 * EMBED, out_b, skip_b, out, EMBED, 2 * EMBED, nullptr);
}

// Round 3
// 306.946 us; speedup vs baseline: 4.1080x; 1.6328x over previous
//
#include <hip/hip_runtime.h>
#include <math.h>

#define EMBED  1024
#define DSTATE 16
#define DCONV  4
#define DTRANK 64
#define BB     2
#define TT     2048
#define M_TOK  (BB*TT)      // 4096 token rows
#define SSMW   96           // dt_rank + 2*DSTATE
#define NCHUNK 64
#define CLEN   (TT/NCHUNK)  // 32

typedef __attribute__((ext_vector_type(8))) __bf16 bf16x8;
typedef __attribute__((ext_vector_type(4))) float floatx4;

__device__ __forceinline__ float silu_f(float x) {
    return x / (1.0f + __expf(-x));
}
__device__ __forceinline__ float softplus_f(float x) {
    return fmaxf(x, 0.0f) + log1pf(__expf(-fabsf(x)));
}
__device__ __forceinline__ unsigned short f2bf(float f) {
    union { float f; unsigned int u; } v; v.f = f;
    unsigned int u = v.u;
    return (unsigned short)((u + 0x7fffu + ((u >> 16) & 1u)) >> 16);
}
__device__ __forceinline__ float bf2f(unsigned short s) {
    union { unsigned int u; float f; } v; v.u = ((unsigned int)s) << 16;
    return v.f;
}
__device__ __forceinline__ void async16(unsigned short* lds, const unsigned short* g) {
    __builtin_amdgcn_global_load_lds(
        (const __attribute__((address_space(1))) unsigned int*)g,
        (__attribute__((address_space(3))) unsigned int*)lds, 16, 0, 0);
}

// ---------------------------------------------------------------------------
// bf16 MFMA GEMM: C[m,n] = sum_k A[m,k]*W[n,k] + bias  (A,W bf16, acc fp32)
// 128x128 tile, BK=32, 256 threads = 4 waves in 2x2, 4x4 16x16x32 tiles/wave.
// EPI: 0 = fp32 store (+bias)            [in_proj -> xr]
//      1 = guarded n<96 fp32 ssm store; n<64 also bf16 into aux  [x_proj]
//      2 = softplus -> bf16 into aux     [dt_proj -> delta]
//      3 = fp32 store + bias + bias2     [fused out+skip -> out]
// ---------------------------------------------------------------------------
template<int EPI>
__global__ __launch_bounds__(256)
void gemm_bf16(const unsigned short* __restrict__ A, int lda,
               const unsigned short* __restrict__ W, int ldw,
               const float* __restrict__ bias, const float* __restrict__ bias2,
               float* __restrict__ C, int ldc, int K,
               unsigned short* __restrict__ aux)
{
    __shared__ unsigned short As[128 * 32];
    __shared__ unsigned short Ws[128 * 32];

    const int tid  = threadIdx.x;
    const int m0   = blockIdx.y * 128;
    const int n0   = blockIdx.x * 128;
    const int wid  = tid >> 6;
    const int lane = tid & 63;
    const int wm   = wid >> 1, wn = wid & 1;
    const int lr   = lane & 15;
    const int lq   = lane >> 4;

    const int l0 = tid,        row0 = l0 >> 2, kc0 = (l0 & 3) * 8;
    const int l1 = tid + 256,  row1 = l1 >> 2, kc1 = (l1 & 3) * 8;

    floatx4 acc[4][4] = {};

    for (int kt = 0; kt < K; kt += 32) {
        async16(&As[l0 * 8], A + (size_t)(m0 + row0) * lda + kt + kc0);
        async16(&As[l1 * 8], A + (size_t)(m0 + row1) * lda + kt + kc1);
        async16(&Ws[l0 * 8], W + (size_t)(n0 + row0) * ldw + kt + kc0);
        async16(&Ws[l1 * 8], W + (size_t)(n0 + row1) * ldw + kt + kc1);
        __syncthreads();

        bf16x8 af[4], bfr[4];
        #pragma unroll
        for (int i = 0; i < 4; ++i)
            af[i] = *(const bf16x8*)&As[(wm * 64 + i * 16 + lr) * 32 + lq * 8];
        #pragma unroll
        for (int i = 0; i < 4; ++i)
            bfr[i] = *(const bf16x8*)&Ws[(wn * 64 + i * 16 + lr) * 32 + lq * 8];

        #pragma unroll
        for (int mi = 0; mi < 4; ++mi)
            #pragma unroll
            for (int ni = 0; ni < 4; ++ni)
                acc[mi][ni] = __builtin_amdgcn_mfma_f32_16x16x32_bf16(
                    af[mi], bfr[ni], acc[mi][ni], 0, 0, 0);
        __syncthreads();
    }

    #pragma unroll
    for (int mi = 0; mi < 4; ++mi) {
        #pragma unroll
        for (int ni = 0; ni < 4; ++ni) {
            int nb = n0 + wn * 64 + ni * 16 + lr;
            #pragma unroll
            for (int r = 0; r < 4; ++r) {
                int m = m0 + wm * 64 + mi * 16 + lq * 4 + r;
                float v = acc[mi][ni][r];
                if (EPI == 0) {
                    C[(size_t)m * ldc + nb] = v + bias[nb];
                } else if (EPI == 1) {
                    if (nb < SSMW) {
                        float o = v + bias[nb];
                        C[(size_t)m * SSMW + nb] = o;
                        if (nb < DTRANK) aux[(size_t)m * DTRANK + nb] = f2bf(o);
                    }
                } else if (EPI == 2) {
                    aux[(size_t)m * ldc + nb] = f2bf(softplus_f(v + bias[nb]));
                } else {
                    C[(size_t)m * ldc + nb] = v + bias[nb] + bias2[nb];
                }
            }
        }
    }
}

// ---------------------------------------------------------------------------
// conversion / packing kernels (fp32 -> bf16)
// ---------------------------------------------------------------------------
__global__ __launch_bounds__(256)
void cvt_f32_bf16(const float* __restrict__ src, unsigned short* __restrict__ dst, int n)
{
    int i = (blockIdx.x * 256 + threadIdx.x) * 4;
    if (i >= n) return;
    float4 v = *(const float4*)&src[i];
    ushort4 o = { f2bf(v.x), f2bf(v.y), f2bf(v.z), f2bf(v.w) };
    *(ushort4*)&dst[i] = o;
}

__global__ __launch_bounds__(256)
void cvt_pad_xp(const float* __restrict__ src, unsigned short* __restrict__ dst)
{
    int i = (blockIdx.x * 256 + threadIdx.x) * 4;
    if (i >= 128 * EMBED) return;
    int row = i >> 10;
    ushort4 o = { 0, 0, 0, 0 };
    if (row < SSMW) {
        float4 v = *(const float4*)&src[i];
        o = { f2bf(v.x), f2bf(v.y), f2bf(v.z), f2bf(v.w) };
    }
    *(ushort4*)&dst[i] = o;
}

__global__ __launch_bounds__(256)
void cvt_cat_w(const float* __restrict__ ow, const float* __restrict__ sw,
               unsigned short* __restrict__ dst)
{
    int i = (blockIdx.x * 256 + threadIdx.x) * 4;
    if (i >= EMBED * 2 * EMBED) return;
    int n = i >> 11, k = i & 2047;
    const float* s = (k < EMBED) ? &ow[(size_t)n * EMBED + k]
                                 : &sw[(size_t)n * EMBED + (k - EMBED)];
    float4 v = *(const float4*)s;
    ushort4 o = { f2bf(v.x), f2bf(v.y), f2bf(v.z), f2bf(v.w) };
    *(ushort4*)&dst[i] = o;
}

__global__ __launch_bounds__(256)
void cvt_x(const float* __restrict__ x, unsigned short* __restrict__ Acat)
{
    int i = (blockIdx.x * 256 + threadIdx.x) * 4;
    if (i >= M_TOK * EMBED) return;
    int m = i >> 10, k = i & 1023;
    float4 v = *(const float4*)&x[i];
    ushort4 o = { f2bf(v.x), f2bf(v.y), f2bf(v.z), f2bf(v.w) };
    *(ushort4*)&Acat[(size_t)m * 2 * EMBED + EMBED + k] = o;
}

// ---------------------------------------------------------------------------
// depthwise causal conv1d (k=4) + bias + SiLU -> xc bf16
// ---------------------------------------------------------------------------
__global__ __launch_bounds__(256)
void conv_silu_kernel(const float* __restrict__ xr,
                      const float* __restrict__ conv_w,
                      const float* __restrict__ conv_b,
                      unsigned short* __restrict__ xcb)
{
    int idx = blockIdx.x * blockDim.x + threadIdx.x;
    if (idx >= BB * TT * EMBED) return;
    int d = idx & (EMBED - 1);
    int t = (idx >> 10) & (TT - 1);
    int b = idx >> 21;

    float w0 = conv_w[d * 4 + 0];
    float w1 = conv_w[d * 4 + 1];
    float w2 = conv_w[d * 4 + 2];
    float w3 = conv_w[d * 4 + 3];

    size_t base = ((size_t)(b * TT + t)) * (2 * EMBED) + d;
    float s = conv_b[d];
    if (t >= 3) s = fmaf(w0, xr[base - 3 * 2 * EMBED], s);
    if (t >= 2) s = fmaf(w1, xr[base - 2 * 2 * EMBED], s);
    if (t >= 1) s = fmaf(w2, xr[base - 1 * 2 * EMBED], s);
    s = fmaf(w3, xr[base], s);
    xcb[(size_t)(b * TT + t) * EMBED + d] = f2bf(silu_f(s));
}

// ---------------------------------------------------------------------------
// Scan pass A: one thread per (b,chunk,d), 16 n-states in registers.
// Stores h_out[16] and S = sum(delta) per chunk (dA-product = exp(An*S)).
// grid = BB*NCHUNK*(EMBED/256) = 512 blocks of 256.
// ---------------------------------------------------------------------------
__global__ __launch_bounds__(256)
void scan_chunk_kernel(const unsigned short* __restrict__ deltab,
                       const unsigned short* __restrict__ xcb,
                       const float* __restrict__ ssm,
                       const float* __restrict__ A_log,
                       float* __restrict__ hio,
                       float* __restrict__ Ssum)
{
    __shared__ float Bs[CLEN][DSTATE];
    const int tid = threadIdx.x;
    const int blk = blockIdx.x;
    const int dg = blk & 3, chunk = (blk >> 2) & (NCHUNK - 1), b = blk >> 8;
    const int d = dg * 256 + tid;
    const int t0 = chunk * CLEN;

    for (int i = tid; i < CLEN * DSTATE; i += 256) {
        int t = i >> 4, n = i & 15;
        Bs[t][n] = ssm[(size_t)(b * TT + t0 + t) * SSMW + DTRANK + n];
    }
    __syncthreads();

    float An[DSTATE];
    #pragma unroll
    for (int n = 0; n < DSTATE; ++n) An[n] = -__expf(A_log[n]);

    float h[DSTATE] = {};
    float S = 0.f;
    for (int t = 0; t < CLEN; ++t) {
        size_t row = (size_t)(b * TT + t0 + t);
        float dv = bf2f(deltab[row * EMBED + d]);
        float xv = bf2f(xcb[row * EMBED + d]);
        S += dv;
        float sx = dv * xv;
        float Bv[DSTATE];
        *(float4*)&Bv[0]  = *(const float4*)&Bs[t][0];
        *(float4*)&Bv[4]  = *(const float4*)&Bs[t][4];
        *(float4*)&Bv[8]  = *(const float4*)&Bs[t][8];
        *(float4*)&Bv[12] = *(const float4*)&Bs[t][12];
        #pragma unroll
        for (int n = 0; n < DSTATE; ++n) {
            float dA = __expf(dv * An[n]);
            h[n] = fmaf(dA, h[n], sx * Bv[n]);
        }
    }
    size_t base = ((size_t)(chunk * BB + b) * EMBED + d) * DSTATE;
    #pragma unroll
    for (int j = 0; j < 4; ++j)
        *(float4*)&hio[base + j * 4] = *(float4*)&h[j * 4];
    Ssum[(size_t)(chunk * BB + b) * EMBED + d] = S;
}

// ---------------------------------------------------------------------------
// Scan pass B: sequential combine over chunks per (b,d,n); h_in overwrites
// h_out in place (read-before-write per offset).
// ---------------------------------------------------------------------------
__global__ __launch_bounds__(256)
void scan_combine_kernel(const float* __restrict__ A_log,
                         const float* __restrict__ Ssum,
                         float* __restrict__ hio)
{
    int idx = blockIdx.x * 256 + threadIdx.x;   // B*EMBED*DSTATE = 32768
    int n  = idx & 15;
    int bd = idx >> 4;
    float An = -__expf(A_log[n]);
    float h = 0.f;
    for (int c = 0; c < NCHUNK; ++c) {
        size_t off = (size_t)c * (BB * EMBED * DSTATE) + idx;
        float ho = hio[off];
        float ap = __expf(An * Ssum[(size_t)c * (BB * EMBED) + bd]);
        hio[off] = h;
        h = fmaf(ap, h, ho);
    }
}

// ---------------------------------------------------------------------------
// Scan pass C: re-scan with h_in; in-register n-reduction; D skip; gate;
// write yb bf16 into Acat[:, 0:1024].
// ---------------------------------------------------------------------------
__global__ __launch_bounds__(256)
void scan_apply_kernel(const unsigned short* __restrict__ deltab,
                       const unsigned short* __restrict__ xcb,
                       const float* __restrict__ ssm,
                       const float* __restrict__ A_log,
                       const float* __restrict__ D_param,
                       const float* __restrict__ xr,
                       const float* __restrict__ hin,
                       unsigned short* __restrict__ Acat)
{
    __shared__ float Bs[CLEN][DSTATE];
    __shared__ float Cs[CLEN][DSTATE];
    const int tid = threadIdx.x;
    const int blk = blockIdx.x;
    const int dg = blk & 3, chunk = (blk >> 2) & (NCHUNK - 1), b = blk >> 8;
    const int d = dg * 256 + tid;
    const int t0 = chunk * CLEN;

    for (int i = tid; i < CLEN * DSTATE; i += 256) {
        int t = i >> 4, n = i & 15;
        size_t row = (size_t)(b * TT + t0 + t);
        Bs[t][n] = ssm[row * SSMW + DTRANK + n];
        Cs[t][n] = ssm[row * SSMW + DTRANK + DSTATE + n];
    }
    __syncthreads();

    float An[DSTATE];
    #pragma unroll
    for (int n = 0; n < DSTATE; ++n) An[n] = -__expf(A_log[n]);
    float Dd = D_param[d];

    float h[DSTATE];
    size_t base = ((size_t)(chunk * BB + b) * EMBED + d) * DSTATE;
    #pragma unroll
    for (int j = 0; j < 4; ++j)
        *(float4*)&h[j * 4] = *(const float4*)&hin[base + j * 4];

    for (int t = 0; t < CLEN; ++t) {
        size_t row = (size_t)(b * TT + t0 + t);
        float dv = bf2f(deltab[row * EMBED + d]);
        float xv = bf2f(xcb[row * EMBED + d]);
        float sx = dv * xv;
        float Bv[DSTATE], Cv[DSTATE];
        *(float4*)&Bv[0]  = *(const float4*)&Bs[t][0];
        *(float4*)&Bv[4]  = *(const float4*)&Bs[t][4];
        *(float4*)&Bv[8]  = *(const float4*)&Bs[t][8];
        *(float4*)&Bv[12] = *(const float4*)&Bs[t][12];
        *(float4*)&Cv[0]  = *(const float4*)&Cs[t][0];
        *(float4*)&Cv[4]  = *(const float4*)&Cs[t][4];
        *(float4*)&Cv[8]  = *(const float4*)&Cs[t][8];
        *(float4*)&Cv[12] = *(const float4*)&Cs[t][12];
        float y0 = 0.f, y1 = 0.f, y2 = 0.f, y3 = 0.f;
        #pragma unroll
        for (int n = 0; n < DSTATE; n += 4) {
            float dA0 = __expf(dv * An[n + 0]);
            float dA1 = __expf(dv * An[n + 1]);
            float dA2 = __expf(dv * An[n + 2]);
            float dA3 = __expf(dv * An[n + 3]);
            h[n + 0] = fmaf(dA0, h[n + 0], sx * Bv[n + 0]);
            h[n + 1] = fmaf(dA1, h[n + 1], sx * Bv[n + 1]);
            h[n + 2] = fmaf(dA2, h[n + 2], sx * Bv[n + 2]);
            h[n + 3] = fmaf(dA3, h[n + 3], sx * Bv[n + 3]);
            y0 = fmaf(h[n + 0], Cv[n + 0], y0);
            y1 = fmaf(h[n + 1], Cv[n + 1], y1);
            y2 = fmaf(h[n + 2], Cv[n + 2], y2);
            y3 = fmaf(h[n + 3], Cv[n + 3], y3);
        }
        float yv = (y0 + y1) + (y2 + y3) + xv * Dd;
        float rv = xr[row * (2 * EMBED) + EMBED + d];
        Acat[row * 2 * EMBED + d] = f2bf(yv * silu_f(rv));
    }
}

// ---------------------------------------------------------------------------
extern "C" void kernel_launch(void* const* d_in, const int* in_sizes, int n_in,
                              void* d_out, int out_size, void* d_ws, size_t ws_size,
                              hipStream_t stream) {
    const float* x      = (const float*)d_in[0];
    const float* in_w   = (const float*)d_in[1];
    const float* in_b   = (const float*)d_in[2];
    const float* conv_w = (const float*)d_in[3];
    const float* conv_b = (const float*)d_in[4];
    const float* xp_w   = (const float*)d_in[5];
    const float* xp_b   = (const float*)d_in[6];
    const float* dt_w   = (const float*)d_in[7];
    const float* dt_b   = (const float*)d_in[8];
    const float* A_log  = (const float*)d_in[9];
    const float* Dp     = (const float*)d_in[10];
    const float* out_w  = (const float*)d_in[11];
    const float* out_b  = (const float*)d_in[12];
    const float* skip_w = (const float*)d_in[13];
    const float* skip_b = (const float*)d_in[14];
    float* out = (float*)d_out;

    // workspace layout
    float* ws    = (float*)d_ws;
    float* xr    = ws;                                    // 4096*2048 fp32
    float* ssm   = xr   + (size_t)M_TOK * 2 * EMBED;      // 4096*96 fp32
    float* hio   = ssm  + (size_t)M_TOK * SSMW;           // 64*2*1024*16 fp32
    float* Ssum  = hio  + (size_t)NCHUNK * BB * EMBED * DSTATE; // 64*2*1024
    unsigned short* Acat = (unsigned short*)(Ssum + (size_t)NCHUNK * BB * EMBED);
    unsigned short* xcb  = Acat + (size_t)M_TOK * 2 * EMBED;
    unsigned short* dltb = xcb  + (size_t)M_TOK * EMBED;
    unsigned short* dtin = dltb + (size_t)M_TOK * EMBED;
    unsigned short* inwb = dtin + (size_t)M_TOK * DTRANK;
    unsigned short* xpwb = inwb + (size_t)2 * EMBED * EMBED;
    unsigned short* dtwb = xpwb + (size_t)128 * EMBED;
    unsigned short* wcat = dtwb + (size_t)EMBED * DTRANK;

    dim3 blk(256);

    // pack weights + x
    cvt_f32_bf16<<<(2 * EMBED * EMBED / 4 + 255) / 256, blk, 0, stream>>>(in_w, inwb, 2 * EMBED * EMBED);
    cvt_f32_bf16<<<(EMBED * DTRANK / 4 + 255) / 256, blk, 0, stream>>>(dt_w, dtwb, EMBED * DTRANK);
    cvt_pad_xp<<<(128 * EMBED / 4 + 255) / 256, blk, 0, stream>>>(xp_w, xpwb);
    cvt_cat_w<<<(EMBED * 2 * EMBED / 4 + 255) / 256, blk, 0, stream>>>(out_w, skip_w, wcat);
    cvt_x<<<(M_TOK * EMBED / 4 + 255) / 256, blk, 0, stream>>>(x, Acat);

    // 1) xr = x @ in_proj_w^T + b   (4096 x 2048, K=1024)
    gemm_bf16<0><<<dim3(2 * EMBED / 128, M_TOK / 128), blk, 0, stream>>>(
        Acat + EMBED, 2 * EMBED, inwb, EMBED, in_b, nullptr, xr, 2 * EMBED, EMBED, nullptr);

    // 2) xc = silu(causal_dwconv + bias) -> bf16
    conv_silu_kernel<<<(M_TOK * EMBED + 255) / 256, blk, 0, stream>>>(xr, conv_w, conv_b, xcb);

    // 3) ssm = xc @ x_proj_w^T + b  (4096 x 96, K=1024); also dtin bf16 (n<64)
    gemm_bf16<1><<<dim3(1, M_TOK / 128), blk, 0, stream>>>(
        xcb, EMBED, xpwb, EMBED, xp_b, nullptr, ssm, SSMW, EMBED, dtin);

    // 4) delta = softplus(dtin @ dt_w^T + b) -> bf16  (4096 x 1024, K=64)
    gemm_bf16<2><<<dim3(EMBED / 128, M_TOK / 128), blk, 0, stream>>>(
        dtin, DTRANK, dtwb, DTRANK, dt_b, nullptr, nullptr, EMBED, DTRANK, dltb);

    // 5) selective scan (3-pass chunked, 16 states/thread)
    scan_chunk_kernel<<<BB * NCHUNK * (EMBED / 256), blk, 0, stream>>>(
        dltb, xcb, ssm, A_log, hio, Ssum);
    scan_combine_kernel<<<(BB * EMBED * DSTATE + 255) / 256, blk, 0, stream>>>(
        A_log, Ssum, hio);
    scan_apply_kernel<<<BB * NCHUNK * (EMBED / 256), blk, 0, stream>>>(
        dltb, xcb, ssm, A_log, Dp, xr, hio, Acat);

    // 6) out = [yb|x] @ [out_w|skip_w]^T + out_b + skip_b  (4096 x 1024, K=2048)
    gemm_bf16<3><<<dim3(EMBED / 128, M_TOK / 128), blk, 0, stream>>>(
        Acat, 2 * EMBED, wcat, 2 * EMBED, out_b, skip_b, out, EMBED, 2 * EMBED, nullptr);
}

// Round 4
// 278.926 us; speedup vs baseline: 4.5207x; 1.1005x over previous
//
#include <hip/hip_runtime.h>
#include <math.h>

#define EMBED  1024
#define DSTATE 16
#define DCONV  4
#define DTRANK 64
#define BB     2
#define TT     2048
#define M_TOK  (BB*TT)      // 4096 token rows
#define SSMW   96           // dt_rank + 2*DSTATE
#define NCHUNK 64
#define CLEN   (TT/NCHUNK)  // 32
#define KSPLIT 8

typedef __attribute__((ext_vector_type(8))) __bf16 bf16x8;
typedef __attribute__((ext_vector_type(4))) float floatx4;

__device__ __forceinline__ float silu_f(float x) {
    return x / (1.0f + __expf(-x));
}
__device__ __forceinline__ float softplus_f(float x) {
    return fmaxf(x, 0.0f) + log1pf(__expf(-fabsf(x)));
}
__device__ __forceinline__ unsigned short f2bf(float f) {
    union { float f; unsigned int u; } v; v.f = f;
    unsigned int u = v.u;
    return (unsigned short)((u + 0x7fffu + ((u >> 16) & 1u)) >> 16);
}
__device__ __forceinline__ float bf2f(unsigned short s) {
    union { unsigned int u; float f; } v; v.u = ((unsigned int)s) << 16;
    return v.f;
}
__device__ __forceinline__ void async16(unsigned short* lds, const unsigned short* g) {
    __builtin_amdgcn_global_load_lds(
        (const __attribute__((address_space(1))) unsigned int*)g,
        (__attribute__((address_space(3))) unsigned int*)lds, 16, 0, 0);
}

// decode helper for the 2x2-wave 128x128 tile
#define GEMM_DECODE \
    const int tid = threadIdx.x; const int wid = tid >> 6; \
    const int lane = tid & 63; \
    const int wm = wid >> 1, wn = wid & 1; \
    const int lr = lane & 15; const int lq = lane >> 4;

// ---------------------------------------------------------------------------
// MFMA core: 128x128 tile, BK=32, 256 thr = 4 waves (2x2), 4x4 16x16x32/wave
// ---------------------------------------------------------------------------
__device__ __forceinline__ void gemm_acc(
    const unsigned short* __restrict__ A, int lda,
    const unsigned short* __restrict__ W, int ldw,
    int m0, int n0, int k0, int klen, floatx4 (&acc)[4][4])
{
    __shared__ unsigned short As[128 * 32];
    __shared__ unsigned short Ws[128 * 32];
    GEMM_DECODE;
    const int l0 = tid,       row0 = l0 >> 2, kc0 = (l0 & 3) * 8;
    const int l1 = tid + 256, row1 = l1 >> 2, kc1 = (l1 & 3) * 8;

    for (int kt = k0; kt < k0 + klen; kt += 32) {
        async16(&As[l0 * 8], A + (size_t)(m0 + row0) * lda + kt + kc0);
        async16(&As[l1 * 8], A + (size_t)(m0 + row1) * lda + kt + kc1);
        async16(&Ws[l0 * 8], W + (size_t)(n0 + row0) * ldw + kt + kc0);
        async16(&Ws[l1 * 8], W + (size_t)(n0 + row1) * ldw + kt + kc1);
        __syncthreads();

        bf16x8 af[4], bfr[4];
        #pragma unroll
        for (int i = 0; i < 4; ++i)
            af[i] = *(const bf16x8*)&As[(wm * 64 + i * 16 + lr) * 32 + lq * 8];
        #pragma unroll
        for (int i = 0; i < 4; ++i)
            bfr[i] = *(const bf16x8*)&Ws[(wn * 64 + i * 16 + lr) * 32 + lq * 8];

        #pragma unroll
        for (int mi = 0; mi < 4; ++mi)
            #pragma unroll
            for (int ni = 0; ni < 4; ++ni)
                acc[mi][ni] = __builtin_amdgcn_mfma_f32_16x16x32_bf16(
                    af[mi], bfr[ni], acc[mi][ni], 0, 0, 0);
        __syncthreads();
    }
}

// ---------------------------------------------------------------------------
// in_proj: [x] @ in_w^T + b.  n<1024 -> xr fp32 (conv input);
//          n>=1024 -> gate = silu(res) bf16
// grid (32, 16): x = m-tile (same-A blocks share XCD), y = n-tile
// ---------------------------------------------------------------------------
__global__ __launch_bounds__(256)
void gemm_in(const unsigned short* __restrict__ A,
             const unsigned short* __restrict__ W,
             const float* __restrict__ bias,
             float* __restrict__ xr, unsigned short* __restrict__ gate)
{
    floatx4 acc[4][4] = {};
    const int m0 = blockIdx.x * 128, n0 = blockIdx.y * 128;
    gemm_acc(A, 2 * EMBED, W, EMBED, m0, n0, 0, EMBED, acc);
    GEMM_DECODE;
    #pragma unroll
    for (int mi = 0; mi < 4; ++mi)
        #pragma unroll
        for (int ni = 0; ni < 4; ++ni) {
            int nb = n0 + wn * 64 + ni * 16 + lr;
            #pragma unroll
            for (int r = 0; r < 4; ++r) {
                int m = m0 + wm * 64 + mi * 16 + lq * 4 + r;
                float v = acc[mi][ni][r] + bias[nb];
                if (nb < EMBED) xr[(size_t)m * EMBED + nb] = v;
                else gate[(size_t)m * EMBED + nb - EMBED] = f2bf(silu_f(v));
            }
        }
}

// ---------------------------------------------------------------------------
// x_proj split-K: grid (32, 1, 8); z = K-slice of 128; partial fp32 out
// ---------------------------------------------------------------------------
__global__ __launch_bounds__(256)
void gemm_xp(const unsigned short* __restrict__ A,
             const unsigned short* __restrict__ W,
             float* __restrict__ xpart)
{
    floatx4 acc[4][4] = {};
    const int m0 = blockIdx.x * 128;
    const int k0 = blockIdx.z * (EMBED / KSPLIT);
    gemm_acc(A, EMBED, W, EMBED, m0, 0, k0, EMBED / KSPLIT, acc);
    GEMM_DECODE;
    float* base = xpart + (size_t)blockIdx.z * M_TOK * SSMW;
    #pragma unroll
    for (int mi = 0; mi < 4; ++mi)
        #pragma unroll
        for (int ni = 0; ni < 4; ++ni) {
            int nb = wn * 64 + ni * 16 + lr;
            if (nb < SSMW) {
                #pragma unroll
                for (int r = 0; r < 4; ++r) {
                    int m = m0 + wm * 64 + mi * 16 + lq * 4 + r;
                    base[(size_t)m * SSMW + nb] = acc[mi][ni][r];
                }
            }
        }
}

__global__ __launch_bounds__(256)
void xp_merge(const float* __restrict__ xpart, const float* __restrict__ xp_b,
              float* __restrict__ ssm, unsigned short* __restrict__ dtin)
{
    int idx = blockIdx.x * 256 + threadIdx.x;    // M_TOK*SSMW
    if (idx >= M_TOK * SSMW) return;
    int m = idx / SSMW, n = idx - m * SSMW;
    float s = xp_b[n];
    #pragma unroll
    for (int z = 0; z < KSPLIT; ++z) s += xpart[(size_t)z * M_TOK * SSMW + idx];
    ssm[idx] = s;
    if (n < DTRANK) dtin[(size_t)m * DTRANK + n] = f2bf(s);
}

// ---------------------------------------------------------------------------
// dt_proj: softplus(dtin @ dt_w^T + b) -> delta bf16.  grid (32, 8)
// ---------------------------------------------------------------------------
__global__ __launch_bounds__(256)
void gemm_dt(const unsigned short* __restrict__ A,
             const unsigned short* __restrict__ W,
             const float* __restrict__ bias,
             unsigned short* __restrict__ dltb)
{
    floatx4 acc[4][4] = {};
    const int m0 = blockIdx.x * 128, n0 = blockIdx.y * 128;
    gemm_acc(A, DTRANK, W, DTRANK, m0, n0, 0, DTRANK, acc);
    GEMM_DECODE;
    #pragma unroll
    for (int mi = 0; mi < 4; ++mi)
        #pragma unroll
        for (int ni = 0; ni < 4; ++ni) {
            int nb = n0 + wn * 64 + ni * 16 + lr;
            #pragma unroll
            for (int r = 0; r < 4; ++r) {
                int m = m0 + wm * 64 + mi * 16 + lq * 4 + r;
                dltb[(size_t)m * EMBED + nb] = f2bf(softplus_f(acc[mi][ni][r] + bias[nb]));
            }
        }
}

// ---------------------------------------------------------------------------
// fused out+skip: [yb|x] @ [ow|sw]^T + ob + sb.  grid (32, 8)
// ---------------------------------------------------------------------------
__global__ __launch_bounds__(256)
void gemm_out(const unsigned short* __restrict__ A,
              const unsigned short* __restrict__ W,
              const float* __restrict__ bias, const float* __restrict__ bias2,
              float* __restrict__ C)
{
    floatx4 acc[4][4] = {};
    const int m0 = blockIdx.x * 128, n0 = blockIdx.y * 128;
    gemm_acc(A, 2 * EMBED, W, 2 * EMBED, m0, n0, 0, 2 * EMBED, acc);
    GEMM_DECODE;
    #pragma unroll
    for (int mi = 0; mi < 4; ++mi)
        #pragma unroll
        for (int ni = 0; ni < 4; ++ni) {
            int nb = n0 + wn * 64 + ni * 16 + lr;
            float bb = bias[nb] + bias2[nb];
            #pragma unroll
            for (int r = 0; r < 4; ++r) {
                int m = m0 + wm * 64 + mi * 16 + lq * 4 + r;
                C[(size_t)m * EMBED + nb] = acc[mi][ni][r] + bb;
            }
        }
}

// ---------------------------------------------------------------------------
// single fused pack kernel: all fp32->bf16 weight/x conversions
// segments in float4 units
// ---------------------------------------------------------------------------
#define SEG0 524288                 // in_w -> inwb
#define SEG1 (SEG0 + 16384)         // dt_w -> dtwb
#define SEG2 (SEG1 + 32768)         // xp_w pad -> xpwb (128x1024)
#define SEG3 (SEG2 + 524288)        // [out_w|skip_w] -> wcat
#define SEG4 (SEG3 + 1048576)       // x -> Acat[:,1024:]

__global__ __launch_bounds__(256)
void cvt_pack(const float* __restrict__ in_w, const float* __restrict__ dt_w,
              const float* __restrict__ xp_w, const float* __restrict__ ow,
              const float* __restrict__ sw, const float* __restrict__ x,
              unsigned short* __restrict__ inwb, unsigned short* __restrict__ dtwb,
              unsigned short* __restrict__ xpwb, unsigned short* __restrict__ wcat,
              unsigned short* __restrict__ Acat)
{
    int j = blockIdx.x * 256 + threadIdx.x;
    if (j >= SEG4) return;
    float4 v = {0.f, 0.f, 0.f, 0.f};
    unsigned short* dst;
    if (j < SEG0) {
        v = *(const float4*)&in_w[j * 4];
        dst = &inwb[j * 4];
    } else if (j < SEG1) {
        int i = (j - SEG0) * 4;
        v = *(const float4*)&dt_w[i];
        dst = &dtwb[i];
    } else if (j < SEG2) {
        int i = (j - SEG1) * 4;
        if ((i >> 10) < SSMW) v = *(const float4*)&xp_w[i];
        dst = &xpwb[i];
    } else if (j < SEG3) {
        int i = (j - SEG2) * 4;
        int n = i >> 11, k = i & 2047;
        v = *(const float4*)((k < EMBED) ? &ow[(size_t)n * EMBED + k]
                                         : &sw[(size_t)n * EMBED + (k - EMBED)]);
        dst = &wcat[i];
    } else {
        int i = (j - SEG3) * 4;
        int m = i >> 10, k = i & 1023;
        v = *(const float4*)&x[i];
        dst = &Acat[(size_t)m * 2 * EMBED + EMBED + k];
    }
    ushort4 o = { f2bf(v.x), f2bf(v.y), f2bf(v.z), f2bf(v.w) };
    *(ushort4*)dst = o;
}

// ---------------------------------------------------------------------------
// depthwise causal conv1d (k=4) + bias + SiLU -> xc bf16; 4 channels/thread
// ---------------------------------------------------------------------------
__global__ __launch_bounds__(256)
void conv_silu(const float* __restrict__ xr,
               const float* __restrict__ conv_w,
               const float* __restrict__ conv_b,
               unsigned short* __restrict__ xcb)
{
    int idx = blockIdx.x * 256 + threadIdx.x;     // over B*T*D/4 = 1M
    if (idx >= BB * TT * EMBED / 4) return;
    int dq = idx & (EMBED / 4 - 1);
    int t  = (idx >> 8) & (TT - 1);
    int b  = idx >> 19;
    int d  = dq * 4;

    float4 cw0 = *(const float4*)&conv_w[(d + 0) * 4];
    float4 cw1 = *(const float4*)&conv_w[(d + 1) * 4];
    float4 cw2 = *(const float4*)&conv_w[(d + 2) * 4];
    float4 cw3 = *(const float4*)&conv_w[(d + 3) * 4];
    float4 s   = *(const float4*)&conv_b[d];

    const float* w0 = (const float*)&cw0;
    const float* w1 = (const float*)&cw1;
    const float* w2 = (const float*)&cw2;
    const float* w3 = (const float*)&cw3;

    #pragma unroll
    for (int jj = 0; jj < 4; ++jj) {
        int tr = t - 3 + jj;
        if (tr >= 0) {
            float4 v = *(const float4*)&xr[(size_t)(b * TT + tr) * EMBED + d];
            s.x = fmaf(w0[jj], v.x, s.x);
            s.y = fmaf(w1[jj], v.y, s.y);
            s.z = fmaf(w2[jj], v.z, s.z);
            s.w = fmaf(w3[jj], v.w, s.w);
        }
    }
    ushort4 o = { f2bf(silu_f(s.x)), f2bf(silu_f(s.y)),
                  f2bf(silu_f(s.z)), f2bf(silu_f(s.w)) };
    *(ushort4*)&xcb[(size_t)(b * TT + t) * EMBED + d] = o;
}

// ---------------------------------------------------------------------------
// Scan pass A: thread per (b,chunk,d), 16 states in regs.
// ---------------------------------------------------------------------------
__global__ __launch_bounds__(256)
void scan_chunk(const unsigned short* __restrict__ deltab,
                const unsigned short* __restrict__ xcb,
                const float* __restrict__ ssm,
                const float* __restrict__ A_log,
                float* __restrict__ hout,
                float* __restrict__ Ssum)
{
    __shared__ float Bs[CLEN][DSTATE];
    const int tid = threadIdx.x;
    const int blk = blockIdx.x;
    const int dg = blk & 3, chunk = (blk >> 2) & (NCHUNK - 1), b = blk >> 8;
    const int d = dg * 256 + tid;
    const int t0 = chunk * CLEN;

    for (int i = tid; i < CLEN * DSTATE; i += 256) {
        int t = i >> 4, n = i & 15;
        Bs[t][n] = ssm[(size_t)(b * TT + t0 + t) * SSMW + DTRANK + n];
    }
    __syncthreads();

    float An[DSTATE];
    #pragma unroll
    for (int n = 0; n < DSTATE; ++n) An[n] = -__expf(A_log[n]);

    float h[DSTATE] = {};
    float S = 0.f;
    for (int t = 0; t < CLEN; ++t) {
        size_t row = (size_t)(b * TT + t0 + t);
        float dv = bf2f(deltab[row * EMBED + d]);
        float xv = bf2f(xcb[row * EMBED + d]);
        S += dv;
        float sx = dv * xv;
        float Bv[DSTATE];
        *(float4*)&Bv[0]  = *(const float4*)&Bs[t][0];
        *(float4*)&Bv[4]  = *(const float4*)&Bs[t][4];
        *(float4*)&Bv[8]  = *(const float4*)&Bs[t][8];
        *(float4*)&Bv[12] = *(const float4*)&Bs[t][12];
        #pragma unroll
        for (int n = 0; n < DSTATE; ++n) {
            float dA = __expf(dv * An[n]);
            h[n] = fmaf(dA, h[n], sx * Bv[n]);
        }
    }
    size_t base = ((size_t)(chunk * BB + b) * EMBED + d) * DSTATE;
    #pragma unroll
    for (int jj = 0; jj < 4; ++jj)
        *(float4*)&hout[base + jj * 4] = *(float4*)&h[jj * 4];
    Ssum[(size_t)(chunk * BB + b) * EMBED + d] = S;
}

// ---------------------------------------------------------------------------
// Scan pass B: combine over chunks; separate hin output + batch-8 prefetch
// ---------------------------------------------------------------------------
__global__ __launch_bounds__(256)
void scan_combine(const float* __restrict__ A_log,
                  const float* __restrict__ Ssum,
                  const float* __restrict__ hout,
                  float* __restrict__ hin)
{
    int idx = blockIdx.x * 256 + threadIdx.x;   // B*EMBED*DSTATE = 32768
    int n  = idx & 15;
    int bd = idx >> 4;
    float An = -__expf(A_log[n]);
    float h = 0.f;
    for (int c0 = 0; c0 < NCHUNK; c0 += 8) {
        float ho[8], S[8];
        #pragma unroll
        for (int jj = 0; jj < 8; ++jj) {
            ho[jj] = hout[(size_t)(c0 + jj) * (BB * EMBED * DSTATE) + idx];
            S[jj]  = Ssum[(size_t)(c0 + jj) * (BB * EMBED) + bd];
        }
        #pragma unroll
        for (int jj = 0; jj < 8; ++jj) {
            hin[(size_t)(c0 + jj) * (BB * EMBED * DSTATE) + idx] = h;
            h = fmaf(__expf(An * S[jj]), h, ho[jj]);
        }
    }
}

// ---------------------------------------------------------------------------
// Scan pass C: re-scan with h_in; n-reduction in regs; D skip; bf16 gate;
// write yb bf16 into Acat[:, 0:1024]
// ---------------------------------------------------------------------------
__global__ __launch_bounds__(256)
void scan_apply(const unsigned short* __restrict__ deltab,
                const unsigned short* __restrict__ xcb,
                const float* __restrict__ ssm,
                const float* __restrict__ A_log,
                const float* __restrict__ D_param,
                const unsigned short* __restrict__ gate,
                const float* __restrict__ hin,
                unsigned short* __restrict__ Acat)
{
    __shared__ float Bs[CLEN][DSTATE];
    __shared__ float Cs[CLEN][DSTATE];
    const int tid = threadIdx.x;
    const int blk = blockIdx.x;
    const int dg = blk & 3, chunk = (blk >> 2) & (NCHUNK - 1), b = blk >> 8;
    const int d = dg * 256 + tid;
    const int t0 = chunk * CLEN;

    for (int i = tid; i < CLEN * DSTATE; i += 256) {
        int t = i >> 4, n = i & 15;
        size_t row = (size_t)(b * TT + t0 + t);
        Bs[t][n] = ssm[row * SSMW + DTRANK + n];
        Cs[t][n] = ssm[row * SSMW + DTRANK + DSTATE + n];
    }
    __syncthreads();

    float An[DSTATE];
    #pragma unroll
    for (int n = 0; n < DSTATE; ++n) An[n] = -__expf(A_log[n]);
    float Dd = D_param[d];

    float h[DSTATE];
    size_t base = ((size_t)(chunk * BB + b) * EMBED + d) * DSTATE;
    #pragma unroll
    for (int jj = 0; jj < 4; ++jj)
        *(float4*)&h[jj * 4] = *(const float4*)&hin[base + jj * 4];

    for (int t = 0; t < CLEN; ++t) {
        size_t row = (size_t)(b * TT + t0 + t);
        float dv = bf2f(deltab[row * EMBED + d]);
        float xv = bf2f(xcb[row * EMBED + d]);
        float sx = dv * xv;
        float Bv[DSTATE], Cv[DSTATE];
        *(float4*)&Bv[0]  = *(const float4*)&Bs[t][0];
        *(float4*)&Bv[4]  = *(const float4*)&Bs[t][4];
        *(float4*)&Bv[8]  = *(const float4*)&Bs[t][8];
        *(float4*)&Bv[12] = *(const float4*)&Bs[t][12];
        *(float4*)&Cv[0]  = *(const float4*)&Cs[t][0];
        *(float4*)&Cv[4]  = *(const float4*)&Cs[t][4];
        *(float4*)&Cv[8]  = *(const float4*)&Cs[t][8];
        *(float4*)&Cv[12] = *(const float4*)&Cs[t][12];
        float y0 = 0.f, y1 = 0.f, y2 = 0.f, y3 = 0.f;
        #pragma unroll
        for (int n = 0; n < DSTATE; n += 4) {
            float dA0 = __expf(dv * An[n + 0]);
            float dA1 = __expf(dv * An[n + 1]);
            float dA2 = __expf(dv * An[n + 2]);
            float dA3 = __expf(dv * An[n + 3]);
            h[n + 0] = fmaf(dA0, h[n + 0], sx * Bv[n + 0]);
            h[n + 1] = fmaf(dA1, h[n + 1], sx * Bv[n + 1]);
            h[n + 2] = fmaf(dA2, h[n + 2], sx * Bv[n + 2]);
            h[n + 3] = fmaf(dA3, h[n + 3], sx * Bv[n + 3]);
            y0 = fmaf(h[n + 0], Cv[n + 0], y0);
            y1 = fmaf(h[n + 1], Cv[n + 1], y1);
            y2 = fmaf(h[n + 2], Cv[n + 2], y2);
            y3 = fmaf(h[n + 3], Cv[n + 3], y3);
        }
        float yv = (y0 + y1) + (y2 + y3) + xv * Dd;
        float g = bf2f(gate[row * EMBED + d]);
        Acat[row * 2 * EMBED + d] = f2bf(yv * g);
    }
}

// ---------------------------------------------------------------------------
extern "C" void kernel_launch(void* const* d_in, const int* in_sizes, int n_in,
                              void* d_out, int out_size, void* d_ws, size_t ws_size,
                              hipStream_t stream) {
    const float* x      = (const float*)d_in[0];
    const float* in_w   = (const float*)d_in[1];
    const float* in_b   = (const float*)d_in[2];
    const float* conv_w = (const float*)d_in[3];
    const float* conv_b = (const float*)d_in[4];
    const float* xp_w   = (const float*)d_in[5];
    const float* xp_b   = (const float*)d_in[6];
    const float* dt_w   = (const float*)d_in[7];
    const float* dt_b   = (const float*)d_in[8];
    const float* A_log  = (const float*)d_in[9];
    const float* Dp     = (const float*)d_in[10];
    const float* out_w  = (const float*)d_in[11];
    const float* out_b  = (const float*)d_in[12];
    const float* skip_w = (const float*)d_in[13];
    const float* skip_b = (const float*)d_in[14];
    float* out = (float*)d_out;

    // workspace layout (fp32 region then bf16 region), ~95 MB total
    float* ws    = (float*)d_ws;
    float* xr    = ws;                                        // 4096*1024
    float* ssm   = xr    + (size_t)M_TOK * EMBED;             // 4096*96
    float* xpart = ssm   + (size_t)M_TOK * SSMW;              // 8*4096*96
    float* hout  = xpart + (size_t)KSPLIT * M_TOK * SSMW;     // 64*2*1024*16
    float* hin   = hout  + (size_t)NCHUNK * BB * EMBED * DSTATE;
    float* Ssum  = hin   + (size_t)NCHUNK * BB * EMBED * DSTATE;  // 64*2*1024
    unsigned short* Acat = (unsigned short*)(Ssum + (size_t)NCHUNK * BB * EMBED);
    unsigned short* xcb  = Acat + (size_t)M_TOK * 2 * EMBED;
    unsigned short* dltb = xcb  + (size_t)M_TOK * EMBED;
    unsigned short* dtin = dltb + (size_t)M_TOK * EMBED;
    unsigned short* gate = dtin + (size_t)M_TOK * DTRANK;
    unsigned short* inwb = gate + (size_t)M_TOK * EMBED;
    unsigned short* xpwb = inwb + (size_t)2 * EMBED * EMBED;
    unsigned short* dtwb = xpwb + (size_t)128 * EMBED;
    unsigned short* wcat = dtwb + (size_t)EMBED * DTRANK;

    dim3 blk(256);

    // 0) pack all weights + x (single kernel)
    cvt_pack<<<(SEG4 + 255) / 256, blk, 0, stream>>>(
        in_w, dt_w, xp_w, out_w, skip_w, x, inwb, dtwb, xpwb, wcat, Acat);

    // 1) in_proj -> xr fp32 (x_in) + gate bf16 (silu(res))
    gemm_in<<<dim3(M_TOK / 128, 2 * EMBED / 128), blk, 0, stream>>>(
        Acat + EMBED, inwb, in_b, xr, gate);

    // 2) conv + silu -> xcb bf16
    conv_silu<<<(M_TOK * EMBED / 4 + 255) / 256, blk, 0, stream>>>(
        xr, conv_w, conv_b, xcb);

    // 3) x_proj split-K8 -> partials; merge -> ssm fp32 + dtin bf16
    gemm_xp<<<dim3(M_TOK / 128, 1, KSPLIT), blk, 0, stream>>>(xcb, xpwb, xpart);
    xp_merge<<<(M_TOK * SSMW + 255) / 256, blk, 0, stream>>>(xpart, xp_b, ssm, dtin);

    // 4) dt_proj -> delta bf16
    gemm_dt<<<dim3(M_TOK / 128, EMBED / 128), blk, 0, stream>>>(
        dtin, dtwb, dt_b, dltb);

    // 5) selective scan (3 passes)
    scan_chunk<<<BB * NCHUNK * (EMBED / 256), blk, 0, stream>>>(
        dltb, xcb, ssm, A_log, hout, Ssum);
    scan_combine<<<(BB * EMBED * DSTATE + 255) / 256, blk, 0, stream>>>(
        A_log, Ssum, hout, hin);
    scan_apply<<<BB * NCHUNK * (EMBED / 256), blk, 0, stream>>>(
        dltb, xcb, ssm, A_log, Dp, gate, hin, Acat);

    // 6) fused out+skip GEMM (K=2048)
    gemm_out<<<dim3(M_TOK / 128, EMBED / 128), blk, 0, stream>>>(
        Acat, wcat, out_b, skip_b, out);
}